// Round 2
// baseline (118.797 us; speedup 1.0000x reference)
//
#include <hip/hip_runtime.h>

// CRF-RNN mean-field, 2 iterations, N=8192, C=4.
// pass1: fused spatial+bilateral Gaussian attention numerators (split-K over j)
// pass2: reduce split-K partials, normalize, apply SK/BK/CM 4x4 matmuls, add unaries.

#define HH 32
#define WW 16
#define DDD 16
#define NN (HH * WW * DDD)   // 8192
#define TI 256               // i-rows per block (1 per thread)
#define NBI (NN / TI)        // 32 i-tiles
#define TJ 256               // j staged per LDS tile

#if __has_builtin(__builtin_amdgcn_exp2f)
#define EXP2(x) __builtin_amdgcn_exp2f(x)
#else
#define EXP2(x) exp2f(x)
#endif

// Per-j LDS record, 16 floats (64B): [0..2]=fs, [3]=-0.5|fs|^2,
// [4..9]=fb, [10]=-0.5|fb|^2, [11..14]=sm, [15]=pad.
struct __align__(16) Rec { float v[16]; };

__device__ __forceinline__ void feats_for(int n, const float* __restrict__ rgb,
                                          float fs[3], float& nhs, float fb[6], float& nhb)
{
    // features pre-scaled by sqrt(log2(e)) so exp(-0.5*d2) == exp2(-0.5*d2_scaled)
    const float SQL2E = 1.2011224087864498f;
    int h = n / (WW * DDD);
    int r = n - h * (WW * DDD);
    int w = r / DDD;
    int d = r - w * DDD;
    float px = (float)(h + 1), py = (float)(w + 1), pz = (float)(d + 1);
    const float ss = SQL2E / 3.0f;   // THETA_GAMMA
    const float sb = SQL2E / 8.0f;   // THETA_ALPHA
    const float sc = SQL2E / 0.5f;   // THETA_BETA
    fs[0] = px * ss; fs[1] = py * ss; fs[2] = pz * ss;
    fb[0] = px * sb; fb[1] = py * sb; fb[2] = pz * sb;
    float c0 = rgb[3 * n + 0], c1 = rgb[3 * n + 1], c2 = rgb[3 * n + 2];
    fb[3] = c0 * sc; fb[4] = c1 * sc; fb[5] = c2 * sc;
    nhs = -0.5f * (fs[0] * fs[0] + fs[1] * fs[1] + fs[2] * fs[2]);
    nhb = -0.5f * (fb[0] * fb[0] + fb[1] * fb[1] + fb[2] * fb[2] +
                   fb[3] * fb[3] + fb[4] * fb[4] + fb[5] * fb[5]);
}

__global__ __launch_bounds__(TI) void crf_pass1(
    const float* __restrict__ qin,   // [N][4] current q (u on iter 1)
    const float* __restrict__ rgb,   // [N][3]
    float* __restrict__ part,        // [kSplit][N][8] partial numerators
    int kSplit)
{
    int kc = blockIdx.x / NBI;
    int ib = blockIdx.x - kc * NBI;
    int tid = threadIdx.x;
    int i = ib * TI + tid;
    int JC = NN / kSplit;
    int j0 = kc * JC;

    float fsi[3], fbi[6], nhsi, nhbi;
    feats_for(i, rgb, fsi, nhsi, fbi, nhbi);

    __shared__ Rec rec[TJ];

    float as0 = 0, as1 = 0, as2 = 0, as3 = 0;
    float ab0 = 0, ab1 = 0, ab2 = 0, ab3 = 0;

    const float L2E = 1.4426950408889634f;

    for (int jt = 0; jt < JC; jt += TJ) {
        int j = j0 + jt + tid;
        float fsj[3], fbj[6], nhsj, nhbj;
        feats_for(j, rgb, fsj, nhsj, fbj, nhbj);
        float q0 = qin[4 * j + 0], q1 = qin[4 * j + 1];
        float q2 = qin[4 * j + 2], q3 = qin[4 * j + 3];
        float m = fmaxf(fmaxf(q0, q1), fmaxf(q2, q3));
        float e0 = EXP2((q0 - m) * L2E), e1 = EXP2((q1 - m) * L2E);
        float e2 = EXP2((q2 - m) * L2E), e3 = EXP2((q3 - m) * L2E);
        float rs = 1.0f / (e0 + e1 + e2 + e3);

        __syncthreads();           // previous tile fully consumed
        float* rv = rec[tid].v;
        rv[0] = fsj[0]; rv[1] = fsj[1]; rv[2] = fsj[2]; rv[3] = nhsj;
        rv[4] = fbj[0]; rv[5] = fbj[1]; rv[6] = fbj[2]; rv[7] = fbj[3];
        rv[8] = fbj[4]; rv[9] = fbj[5]; rv[10] = nhbj;
        rv[11] = e0 * rs; rv[12] = e1 * rs; rv[13] = e2 * rs; rv[14] = e3 * rs;
        rv[15] = 0.0f;
        __syncthreads();

        #pragma unroll 4
        for (int jj = 0; jj < TJ; ++jj) {
            const float4 r0 = *((const float4*)&rec[jj].v[0]);
            const float4 r1 = *((const float4*)&rec[jj].v[4]);
            const float4 r2 = *((const float4*)&rec[jj].v[8]);
            const float4 r3 = *((const float4*)&rec[jj].v[12]);
            float args = nhsi + r0.w;
            args = fmaf(fsi[0], r0.x, args);
            args = fmaf(fsi[1], r0.y, args);
            args = fmaf(fsi[2], r0.z, args);
            float argb = nhbi + r2.z;
            argb = fmaf(fbi[0], r1.x, argb);
            argb = fmaf(fbi[1], r1.y, argb);
            argb = fmaf(fbi[2], r1.z, argb);
            argb = fmaf(fbi[3], r1.w, argb);
            argb = fmaf(fbi[4], r2.x, argb);
            argb = fmaf(fbi[5], r2.y, argb);
            float ws = EXP2(args);
            float wb = EXP2(argb);
            as0 = fmaf(ws, r2.w, as0);
            as1 = fmaf(ws, r3.x, as1);
            as2 = fmaf(ws, r3.y, as2);
            as3 = fmaf(ws, r3.z, as3);
            ab0 = fmaf(wb, r2.w, ab0);
            ab1 = fmaf(wb, r3.x, ab1);
            ab2 = fmaf(wb, r3.y, ab2);
            ab3 = fmaf(wb, r3.z, ab3);
        }
    }

    float4* p4 = (float4*)(part + ((size_t)kc * NN + i) * 8);
    p4[0] = make_float4(as0, as1, as2, as3);
    p4[1] = make_float4(ab0, ab1, ab2, ab3);
}

__global__ __launch_bounds__(256) void crf_pass2(
    const float* __restrict__ part, int kSplit,
    const float* __restrict__ u,
    const float* __restrict__ sk, const float* __restrict__ bk,
    const float* __restrict__ cm,
    float* __restrict__ qout)
{
    int i = blockIdx.x * 256 + threadIdx.x;
    float as[4] = {0, 0, 0, 0}, ab[4] = {0, 0, 0, 0};
    for (int kc = 0; kc < kSplit; ++kc) {
        const float4* p4 = (const float4*)(part + ((size_t)kc * NN + i) * 8);
        float4 a = p4[0], b = p4[1];
        as[0] += a.x; as[1] += a.y; as[2] += a.z; as[3] += a.w;
        ab[0] += b.x; ab[1] += b.y; ab[2] += b.z; ab[3] += b.w;
    }
    // softmax denominators = sum of numerators (sum_c sm_c == 1)
    float rs = 1.0f / (as[0] + as[1] + as[2] + as[3]);
    float rb = 1.0f / (ab[0] + ab[1] + ab[2] + ab[3]);
    float so[4], bo[4];
    #pragma unroll
    for (int c = 0; c < 4; ++c) { so[c] = as[c] * rs; bo[c] = ab[c] * rb; }
    float msg[4];
    #pragma unroll
    for (int c = 0; c < 4; ++c) {
        float m = 0.0f;
        #pragma unroll
        for (int d = 0; d < 4; ++d)
            m += sk[c * 4 + d] * so[d] + bk[c * 4 + d] * bo[d];
        msg[c] = m;
    }
    #pragma unroll
    for (int c = 0; c < 4; ++c) {
        float pw = 0.0f;
        #pragma unroll
        for (int d = 0; d < 4; ++d) pw += cm[c * 4 + d] * msg[d];
        qout[4 * i + c] = u[4 * i + c] + pw;
    }
}

extern "C" void kernel_launch(void* const* d_in, const int* in_sizes, int n_in,
                              void* d_out, int out_size, void* d_ws, size_t ws_size,
                              hipStream_t stream)
{
    const float* u   = (const float*)d_in[0];
    const float* rgb = (const float*)d_in[1];
    const float* sk  = (const float*)d_in[2];
    const float* bk  = (const float*)d_in[3];
    const float* cm  = (const float*)d_in[4];
    float* out = (float*)d_out;

    // pick largest split-K that fits the workspace (partials + q ping buffer)
    int kSplit = 32;
    while (kSplit > 1 &&
           ((size_t)kSplit * NN * 8 + (size_t)NN * 4) * sizeof(float) > ws_size)
        kSplit >>= 1;

    float* part = (float*)d_ws;
    float* qbuf = part + (size_t)kSplit * NN * 8;

    dim3 blk(TI);
    dim3 g1(NBI * kSplit);
    dim3 g2(NN / 256);

    // iteration 1: q = u
    crf_pass1<<<g1, blk, 0, stream>>>(u, rgb, part, kSplit);
    crf_pass2<<<g2, blk, 0, stream>>>(part, kSplit, u, sk, bk, cm, qbuf);
    // iteration 2
    crf_pass1<<<g1, blk, 0, stream>>>(qbuf, rgb, part, kSplit);
    crf_pass2<<<g2, blk, 0, stream>>>(part, kSplit, u, sk, bk, cm, out);
}